// Round 1
// baseline (1658.253 us; speedup 1.0000x reference)
//
#include <hip/hip_runtime.h>
#include <hip/hip_bf16.h>
#include <math.h>

// Problem constants (from reference):
//   N = 500000 nodes, F = H = 128, S = 256 segments.
// out = tanh( mlp_l(x) + pooled[seg] ),  pooled = segment_mean( mlp_g(x) )
// fp32 throughout (no fp32 MFMA on CDNA4 -> vector ALU GEMM, round-0 baseline).

#define FW 128          // feature/hidden width
#define SEGS 256
#define TILE_R 64       // rows per block
#define LSTR 132        // LDS row stride (pad +4: 4-row-apart reads land on 2 banks, 2-way = free)

// --- kernel 1: per-segment 1/count via binary search over sorted segment_ids ---
__global__ void counts_kernel(const int* __restrict__ seg, float* __restrict__ inv_counts, int N) {
    int s = threadIdx.x;            // one block of 256 threads
    // lower_bound(v): first idx with seg[idx] >= v
    int lo0 = 0, hi0 = N;
    while (lo0 < hi0) { int mid = (lo0 + hi0) >> 1; if (seg[mid] < s) lo0 = mid + 1; else hi0 = mid; }
    int lo1 = 0, hi1 = N;
    while (lo1 < hi1) { int mid = (lo1 + hi1) >> 1; if (seg[mid] < s + 1) lo1 = mid + 1; else hi1 = mid; }
    int c = lo1 - lo0;
    inv_counts[s] = 1.0f / (float)(c > 0 ? c : 1);
}

// --- shared GEMM body: buf holds x tile; compute h=relu(x@W1+b1) in-place, then y=h@W2+b2 in acc ---
// Thread layout: 256 threads = 16(ty) x 16(tx); each thread owns 4 rows x 8 cols.
__device__ __forceinline__ void two_layer_mlp(
    float* buf,                               // [TILE_R * LSTR] LDS, holds x tile on entry
    const float* __restrict__ W1, const float* __restrict__ b1,
    const float* __restrict__ W2, const float* __restrict__ b2,
    int row_base, int col_base, float acc[4][8])
{
    // ---- stage 1: h = relu(x @ W1 + b1) ----
    float h[4][8];
    {
        float4 bl0 = *(const float4*)&b1[col_base];
        float4 bl1 = *(const float4*)&b1[col_base + 4];
        #pragma unroll
        for (int r = 0; r < 4; ++r) {
            h[r][0] = bl0.x; h[r][1] = bl0.y; h[r][2] = bl0.z; h[r][3] = bl0.w;
            h[r][4] = bl1.x; h[r][5] = bl1.y; h[r][6] = bl1.z; h[r][7] = bl1.w;
        }
    }
    #pragma unroll 8
    for (int k = 0; k < FW; ++k) {
        float a0 = buf[(row_base + 0) * LSTR + k];
        float a1 = buf[(row_base + 1) * LSTR + k];
        float a2 = buf[(row_base + 2) * LSTR + k];
        float a3 = buf[(row_base + 3) * LSTR + k];
        float4 w0 = *(const float4*)&W1[k * FW + col_base];
        float4 w1 = *(const float4*)&W1[k * FW + col_base + 4];
        float w[8] = {w0.x, w0.y, w0.z, w0.w, w1.x, w1.y, w1.z, w1.w};
        #pragma unroll
        for (int c = 0; c < 8; ++c) {
            h[0][c] = fmaf(a0, w[c], h[0][c]);
            h[1][c] = fmaf(a1, w[c], h[1][c]);
            h[2][c] = fmaf(a2, w[c], h[2][c]);
            h[3][c] = fmaf(a3, w[c], h[3][c]);
        }
    }
    __syncthreads();                 // all x reads done -> safe to overwrite buf with h
    #pragma unroll
    for (int r = 0; r < 4; ++r)
        #pragma unroll
        for (int c = 0; c < 8; ++c)
            buf[(row_base + r) * LSTR + col_base + c] = fmaxf(h[r][c], 0.0f);
    __syncthreads();

    // ---- stage 2: y = h @ W2 + b2 ----
    {
        float4 bl0 = *(const float4*)&b2[col_base];
        float4 bl1 = *(const float4*)&b2[col_base + 4];
        #pragma unroll
        for (int r = 0; r < 4; ++r) {
            acc[r][0] = bl0.x; acc[r][1] = bl0.y; acc[r][2] = bl0.z; acc[r][3] = bl0.w;
            acc[r][4] = bl1.x; acc[r][5] = bl1.y; acc[r][6] = bl1.z; acc[r][7] = bl1.w;
        }
    }
    #pragma unroll 8
    for (int k = 0; k < FW; ++k) {
        float a0 = buf[(row_base + 0) * LSTR + k];
        float a1 = buf[(row_base + 1) * LSTR + k];
        float a2 = buf[(row_base + 2) * LSTR + k];
        float a3 = buf[(row_base + 3) * LSTR + k];
        float4 w0 = *(const float4*)&W2[k * FW + col_base];
        float4 w1 = *(const float4*)&W2[k * FW + col_base + 4];
        float w[8] = {w0.x, w0.y, w0.z, w0.w, w1.x, w1.y, w1.z, w1.w};
        #pragma unroll
        for (int c = 0; c < 8; ++c) {
            acc[0][c] = fmaf(a0, w[c], acc[0][c]);
            acc[1][c] = fmaf(a1, w[c], acc[1][c]);
            acc[2][c] = fmaf(a2, w[c], acc[2][c]);
            acc[3][c] = fmaf(a3, w[c], acc[3][c]);
        }
    }
}

// --- stage x tile into LDS (float4, coalesced), zero-fill OOB rows ---
__device__ __forceinline__ void stage_x(float* buf, const float* __restrict__ x, int r0, int N) {
    const float4* x4 = (const float4*)x;
    const int tile_f4 = TILE_R * (FW / 4);     // 2048 float4
    for (int j = threadIdx.x; j < tile_f4; j += 256) {
        int row = j >> 5;                       // j / (FW/4)
        int col = (j & 31) << 2;
        float4 v = make_float4(0.f, 0.f, 0.f, 0.f);
        if (r0 + row < N) v = x4[(long)r0 * (FW / 4) + j];
        *(float4*)&buf[row * LSTR + col] = v;
    }
}

// --- pass A: gamma branch + segment-sum (mean folded via inv_counts) ---
__global__ __launch_bounds__(256) void gamma_kernel(
    const float* __restrict__ x, const int* __restrict__ seg,
    const float* __restrict__ W1, const float* __restrict__ b1,
    const float* __restrict__ W2, const float* __restrict__ b2,
    const float* __restrict__ inv_counts, float* __restrict__ pooled, int N)
{
    __shared__ float buf[TILE_R * LSTR];
    __shared__ int   segs[TILE_R];

    int tid = threadIdx.x;
    int r0 = blockIdx.x * TILE_R;
    stage_x(buf, x, r0, N);
    if (tid < TILE_R) segs[tid] = (r0 + tid < N) ? seg[r0 + tid] : -1;
    __syncthreads();

    int ty = tid >> 4, tx = tid & 15;
    int row_base = ty * 4, col_base = tx * 8;
    float acc[4][8];
    two_layer_mlp(buf, W1, b1, W2, b2, row_base, col_base, acc);

    __syncthreads();                 // all h reads done -> overwrite buf with gamma
    #pragma unroll
    for (int r = 0; r < 4; ++r)
        #pragma unroll
        for (int c = 0; c < 8; ++c)
            buf[(row_base + r) * LSTR + col_base + c] = acc[r][c];
    __syncthreads();

    // segment reduction: f = tid&127 owns one feature; two halves of 32 rows each.
    int f = tid & 127;
    int rbeg = (tid >> 7) * 32, rend = rbeg + 32;
    float accum = 0.0f;
    int cur = segs[rbeg];
    for (int r = rbeg; r < rend; ++r) {
        int s = segs[r];
        if (s != cur) {
            if (cur >= 0) atomicAdd(&pooled[cur * FW + f], accum * inv_counts[cur]);
            accum = 0.0f; cur = s;
        }
        accum += buf[r * LSTR + f];
    }
    if (cur >= 0) atomicAdd(&pooled[cur * FW + f], accum * inv_counts[cur]);
}

// --- pass B: lambda branch + pooled add + tanh, direct store ---
__global__ __launch_bounds__(256) void lambda_kernel(
    const float* __restrict__ x, const int* __restrict__ seg,
    const float* __restrict__ W1, const float* __restrict__ b1,
    const float* __restrict__ W2, const float* __restrict__ b2,
    const float* __restrict__ pooled, float* __restrict__ out, int N)
{
    __shared__ float buf[TILE_R * LSTR];
    __shared__ int   segs[TILE_R];

    int tid = threadIdx.x;
    int r0 = blockIdx.x * TILE_R;
    stage_x(buf, x, r0, N);
    if (tid < TILE_R) segs[tid] = (r0 + tid < N) ? seg[r0 + tid] : -1;
    __syncthreads();

    int ty = tid >> 4, tx = tid & 15;
    int row_base = ty * 4, col_base = tx * 8;
    float acc[4][8];
    two_layer_mlp(buf, W1, b1, W2, b2, row_base, col_base, acc);

    #pragma unroll
    for (int r = 0; r < 4; ++r) {
        int row = r0 + row_base + r;
        if (row >= N) continue;
        int s = segs[row_base + r];
        float4 p0 = *(const float4*)&pooled[s * FW + col_base];
        float4 p1 = *(const float4*)&pooled[s * FW + col_base + 4];
        float4 o0, o1;
        o0.x = tanhf(acc[r][0] + p0.x); o0.y = tanhf(acc[r][1] + p0.y);
        o0.z = tanhf(acc[r][2] + p0.z); o0.w = tanhf(acc[r][3] + p0.w);
        o1.x = tanhf(acc[r][4] + p1.x); o1.y = tanhf(acc[r][5] + p1.y);
        o1.z = tanhf(acc[r][6] + p1.z); o1.w = tanhf(acc[r][7] + p1.w);
        *(float4*)&out[(long)row * FW + col_base]     = o0;
        *(float4*)&out[(long)row * FW + col_base + 4] = o1;
    }
}

extern "C" void kernel_launch(void* const* d_in, const int* in_sizes, int n_in,
                              void* d_out, int out_size, void* d_ws, size_t ws_size,
                              hipStream_t stream) {
    const float* x   = (const float*)d_in[0];
    const int*   seg = (const int*)  d_in[1];
    const float* lW1 = (const float*)d_in[2];
    const float* lb1 = (const float*)d_in[3];
    const float* lW2 = (const float*)d_in[4];
    const float* lb2 = (const float*)d_in[5];
    const float* gW1 = (const float*)d_in[6];
    const float* gb1 = (const float*)d_in[7];
    const float* gW2 = (const float*)d_in[8];
    const float* gb2 = (const float*)d_in[9];
    float* out = (float*)d_out;

    const int N = in_sizes[0] / FW;            // 500000

    float* pooled     = (float*)d_ws;          // SEGS * FW fp32 sums->means
    float* inv_counts = pooled + SEGS * FW;    // SEGS fp32

    hipMemsetAsync(pooled, 0, SEGS * FW * sizeof(float), stream);
    counts_kernel<<<1, 256, 0, stream>>>(seg, inv_counts, N);

    int nb = (N + TILE_R - 1) / TILE_R;        // 7813
    gamma_kernel<<<nb, 256, 0, stream>>>(x, seg, gW1, gb1, gW2, gb2, inv_counts, pooled, N);
    lambda_kernel<<<nb, 256, 0, stream>>>(x, seg, lW1, lb1, lW2, lb2, pooled, out, N);
}

// Round 2
// 729.408 us; speedup vs baseline: 2.2734x; 2.2734x over previous
//
#include <hip/hip_runtime.h>
#include <hip/hip_bf16.h>
#include <math.h>

// N=500000, F=H=128, S=256.
// out = tanh( mlp_l(x) + pooled[seg] ), pooled = segment_mean( mlp_g(x) )
// bf16 MFMA (16x16x32) with hi/lo split A-operand for accuracy:
//   x = x_hi + x_lo (both bf16), h likewise; W single bf16.
//   -> residual error is W-rounding only (~0.001 std/layer), absmax ~0.01 < 0.02.

#define FW 128
#define SEGS 256
#define TILE_R 64
#define ASTR 136     // bf16 row stride: byte stride 272 -> dword stride 68 = 4 mod 32 -> 2-way (free)
#define GSTR 132     // fp32 row stride for gamma reduction buffer (4*132 = 16 mod 32 -> 2-way)

typedef __attribute__((ext_vector_type(8))) short bf16x8;
typedef __attribute__((ext_vector_type(4))) float f32x4;

__device__ __forceinline__ short f2bf(float f) {
    unsigned u = __builtin_bit_cast(unsigned, f);
    u += 0x7FFF + ((u >> 16) & 1);               // RNE
    return (short)(u >> 16);
}
__device__ __forceinline__ float bf2f(short s) {
    unsigned u = ((unsigned)(unsigned short)s) << 16;
    return __builtin_bit_cast(float, u);
}
__device__ __forceinline__ float fast_tanh(float x) {
    float ax = fabsf(x);
    float t = __expf(-2.0f * ax);                // exp2-based, ~1e-6 rel err
    float r = (1.0f - t) / (1.0f + t);
    return __builtin_copysignf(r, x);
}

// --- per-segment 1/count via binary search over sorted segment_ids ---
__global__ void counts_kernel(const int* __restrict__ seg, float* __restrict__ inv_counts, int N) {
    int s = threadIdx.x;
    int lo0 = 0, hi0 = N;
    while (lo0 < hi0) { int mid = (lo0 + hi0) >> 1; if (seg[mid] < s) lo0 = mid + 1; else hi0 = mid; }
    int lo1 = 0, hi1 = N;
    while (lo1 < hi1) { int mid = (lo1 + hi1) >> 1; if (seg[mid] < s + 1) lo1 = mid + 1; else hi1 = mid; }
    int c = lo1 - lo0;
    inv_counts[s] = 1.0f / (float)(c > 0 ? c : 1);
}

// --- pack W[128][128] fp32 row-major -> B-fragment-ordered bf16 ---
// frag f = nt*4 + ks; lane l; Wp[(f*64+l)] = 8 bf16: W[ks*32 + (l>>4)*8 + j][nt*16 + (l&15)]
__global__ void packW_kernel(const float* __restrict__ W0, const float* __restrict__ W1,
                             const float* __restrict__ W2, const float* __restrict__ W3,
                             uint4* __restrict__ P0, uint4* __restrict__ P1,
                             uint4* __restrict__ P2, uint4* __restrict__ P3) {
    const float* W = blockIdx.x == 0 ? W0 : blockIdx.x == 1 ? W1 : blockIdx.x == 2 ? W2 : W3;
    uint4*       P = blockIdx.x == 0 ? P0 : blockIdx.x == 1 ? P1 : blockIdx.x == 2 ? P2 : P3;
    for (int s = threadIdx.x; s < 32 * 64; s += 256) {
        int f = s >> 6, l = s & 63;
        int nt = f >> 2, ks = f & 3;
        int n = nt * 16 + (l & 15);
        int k0 = ks * 32 + ((l >> 4) << 3);
        union { short sh[8]; uint4 q; } u;
        #pragma unroll
        for (int j = 0; j < 8; ++j) u.sh[j] = f2bf(W[(k0 + j) * FW + n]);
        P[s] = u.q;
    }
}

// --- two-layer MLP core: Ahi/Alo hold split-x on entry, split-h after layer 1.
// Each wave computes 16 rows x 128 cols; acc2 = h@W2 (pre-bias) in C/D layout. ---
__device__ __forceinline__ void mlp_core(
    short* Ahi, short* Alo,
    const uint4* __restrict__ Wp1, const float* __restrict__ b1,
    const uint4* __restrict__ Wp2,
    int wv, int lane, f32x4 acc2[8])
{
    int l15 = lane & 15, q = lane >> 4;
    int abase = (wv * 16 + l15) * ASTR + q * 8;   // shorts

    f32x4 acc1[8];
    #pragma unroll
    for (int nt = 0; nt < 8; ++nt) acc1[nt] = (f32x4){0.f, 0.f, 0.f, 0.f};
    #pragma unroll
    for (int ks = 0; ks < 4; ++ks) {
        bf16x8 ahi = *(bf16x8*)&Ahi[abase + ks * 32];
        bf16x8 alo = *(bf16x8*)&Alo[abase + ks * 32];
        #pragma unroll
        for (int nt = 0; nt < 8; ++nt) {
            bf16x8 b = __builtin_bit_cast(bf16x8, Wp1[(nt * 4 + ks) * 64 + lane]);
            acc1[nt] = __builtin_amdgcn_mfma_f32_16x16x32_bf16(ahi, b, acc1[nt], 0, 0, 0);
            acc1[nt] = __builtin_amdgcn_mfma_f32_16x16x32_bf16(alo, b, acc1[nt], 0, 0, 0);
        }
    }
    __syncthreads();   // all x reads done before in-place h overwrite

    // epilogue 1: h = relu(acc1 + b1), split hi/lo, store (rows are wave-private)
    #pragma unroll
    for (int nt = 0; nt < 8; ++nt) {
        float bias = b1[nt * 16 + l15];
        #pragma unroll
        for (int r = 0; r < 4; ++r) {
            int row = wv * 16 + q * 4 + r;
            float h = fmaxf(acc1[nt][r] + bias, 0.f);
            short hi = f2bf(h);
            short lo = f2bf(h - bf2f(hi));
            Ahi[row * ASTR + nt * 16 + l15] = hi;
            Alo[row * ASTR + nt * 16 + l15] = lo;
        }
    }
    __syncthreads();   // cross-lane RAW on h

    #pragma unroll
    for (int nt = 0; nt < 8; ++nt) acc2[nt] = (f32x4){0.f, 0.f, 0.f, 0.f};
    #pragma unroll
    for (int ks = 0; ks < 4; ++ks) {
        bf16x8 ahi = *(bf16x8*)&Ahi[abase + ks * 32];
        bf16x8 alo = *(bf16x8*)&Alo[abase + ks * 32];
        #pragma unroll
        for (int nt = 0; nt < 8; ++nt) {
            bf16x8 b = __builtin_bit_cast(bf16x8, Wp2[(nt * 4 + ks) * 64 + lane]);
            acc2[nt] = __builtin_amdgcn_mfma_f32_16x16x32_bf16(ahi, b, acc2[nt], 0, 0, 0);
            acc2[nt] = __builtin_amdgcn_mfma_f32_16x16x32_bf16(alo, b, acc2[nt], 0, 0, 0);
        }
    }
}

// --- stage x tile: fp32 -> split bf16 hi/lo in LDS ---
__device__ __forceinline__ void stage_x(short* Ahi, short* Alo, const float* __restrict__ x,
                                        int r0, int N) {
    const float4* x4 = (const float4*)x;
    for (int j = threadIdx.x; j < TILE_R * 32; j += 256) {
        int row = j >> 5, c4 = j & 31;
        float4 v = make_float4(0.f, 0.f, 0.f, 0.f);
        if (r0 + row < N) v = x4[(long)r0 * 32 + j];
        short4 hi, lo;
        hi.x = f2bf(v.x); lo.x = f2bf(v.x - bf2f(hi.x));
        hi.y = f2bf(v.y); lo.y = f2bf(v.y - bf2f(hi.y));
        hi.z = f2bf(v.z); lo.z = f2bf(v.z - bf2f(hi.z));
        hi.w = f2bf(v.w); lo.w = f2bf(v.w - bf2f(hi.w));
        *(short4*)&Ahi[row * ASTR + c4 * 4] = hi;
        *(short4*)&Alo[row * ASTR + c4 * 4] = lo;
    }
}

// --- pass A: gamma branch + segment-mean accumulation ---
__global__ __launch_bounds__(256) void gamma_kernel(
    const float* __restrict__ x, const int* __restrict__ seg,
    const uint4* __restrict__ Wp1, const float* __restrict__ b1,
    const uint4* __restrict__ Wp2, const float* __restrict__ b2,
    const float* __restrict__ inv_counts, float* __restrict__ pooled, int N)
{
    __shared__ short smem[2 * TILE_R * ASTR];
    __shared__ int   segs[TILE_R];
    short* Ahi = smem;
    short* Alo = smem + TILE_R * ASTR;
    float* gbuf = (float*)smem;                 // aliases A bufs; 64*132*4 = 33792 <= 34816 B

    int tid = threadIdx.x;
    int r0 = blockIdx.x * TILE_R;
    stage_x(Ahi, Alo, x, r0, N);
    if (tid < TILE_R) segs[tid] = (r0 + tid < N) ? seg[r0 + tid] : -1;
    __syncthreads();

    int wv = tid >> 6, lane = tid & 63;
    f32x4 acc2[8];
    mlp_core(Ahi, Alo, Wp1, b1, Wp2, wv, lane, acc2);

    __syncthreads();   // before clobbering smem as gbuf (cross-wave WAR)
    int l15 = lane & 15, q = lane >> 4;
    #pragma unroll
    for (int nt = 0; nt < 8; ++nt) {
        float bias = b2[nt * 16 + l15];
        #pragma unroll
        for (int r = 0; r < 4; ++r) {
            int row = wv * 16 + q * 4 + r;
            gbuf[row * GSTR + nt * 16 + l15] = acc2[nt][r] + bias;
        }
    }
    __syncthreads();

    // segmented reduction over sorted segs; mean folded via inv_counts
    int f = tid & 127;
    int rbeg = (tid >> 7) * 32, rend = rbeg + 32;
    float accum = 0.f;
    int cur = segs[rbeg];
    for (int r = rbeg; r < rend; ++r) {
        int s = segs[r];
        if (s != cur) {
            if (cur >= 0) atomicAdd(&pooled[cur * FW + f], accum * inv_counts[cur]);
            accum = 0.f; cur = s;
        }
        accum += gbuf[r * GSTR + f];
    }
    if (cur >= 0) atomicAdd(&pooled[cur * FW + f], accum * inv_counts[cur]);
}

// --- pass B: lambda branch + pooled + tanh, direct store ---
__global__ __launch_bounds__(256) void lambda_kernel(
    const float* __restrict__ x, const int* __restrict__ seg,
    const uint4* __restrict__ Wp1, const float* __restrict__ b1,
    const uint4* __restrict__ Wp2, const float* __restrict__ b2,
    const float* __restrict__ pooled, float* __restrict__ out, int N)
{
    __shared__ short smem[2 * TILE_R * ASTR];
    __shared__ int   segs[TILE_R];
    short* Ahi = smem;
    short* Alo = smem + TILE_R * ASTR;

    int tid = threadIdx.x;
    int r0 = blockIdx.x * TILE_R;
    stage_x(Ahi, Alo, x, r0, N);
    if (tid < TILE_R) segs[tid] = (r0 + tid < N) ? seg[r0 + tid] : -1;
    __syncthreads();

    int wv = tid >> 6, lane = tid & 63;
    f32x4 acc2[8];
    mlp_core(Ahi, Alo, Wp1, b1, Wp2, wv, lane, acc2);

    int l15 = lane & 15, q = lane >> 4;
    #pragma unroll
    for (int nt = 0; nt < 8; ++nt) {
        float bias = b2[nt * 16 + l15];
        #pragma unroll
        for (int r = 0; r < 4; ++r) {
            int lrow = wv * 16 + q * 4 + r;
            int row = r0 + lrow;
            if (row < N) {
                int s = segs[lrow];
                float p = pooled[s * FW + nt * 16 + l15];
                out[(long)row * FW + nt * 16 + l15] = fast_tanh(acc2[nt][r] + bias + p);
            }
        }
    }
}

extern "C" void kernel_launch(void* const* d_in, const int* in_sizes, int n_in,
                              void* d_out, int out_size, void* d_ws, size_t ws_size,
                              hipStream_t stream) {
    const float* x   = (const float*)d_in[0];
    const int*   seg = (const int*)  d_in[1];
    const float* lW1 = (const float*)d_in[2];
    const float* lb1 = (const float*)d_in[3];
    const float* lW2 = (const float*)d_in[4];
    const float* lb2 = (const float*)d_in[5];
    const float* gW1 = (const float*)d_in[6];
    const float* gb1 = (const float*)d_in[7];
    const float* gW2 = (const float*)d_in[8];
    const float* gb2 = (const float*)d_in[9];
    float* out = (float*)d_out;

    const int N = in_sizes[0] / FW;            // 500000

    char* ws = (char*)d_ws;
    float* pooled     = (float*)ws;                         // 256*128*4 = 131072 B
    float* inv_counts = (float*)(ws + 131072);              // 1024 B
    uint4* WpL1 = (uint4*)(ws + 132096);                    // 32 KB each
    uint4* WpL2 = WpL1 + 2048;
    uint4* WpG1 = WpL2 + 2048;
    uint4* WpG2 = WpG1 + 2048;

    hipMemsetAsync(pooled, 0, SEGS * FW * sizeof(float), stream);
    counts_kernel<<<1, 256, 0, stream>>>(seg, inv_counts, N);
    packW_kernel<<<4, 256, 0, stream>>>(lW1, lW2, gW1, gW2, WpL1, WpL2, WpG1, WpG2);

    int nb = (N + TILE_R - 1) / TILE_R;        // 7813
    gamma_kernel<<<nb, 256, 0, stream>>>(x, seg, WpG1, gb1, WpG2, gb2, inv_counts, pooled, N);
    lambda_kernel<<<nb, 256, 0, stream>>>(x, seg, WpL1, lb1, WpL2, lb2, pooled, out, N);
}